// Round 21
// baseline (90.542 us; speedup 1.0000x reference)
//
#include <hip/hip_runtime.h>

#define BB 16
#define CC 256
#define NN 4096
#define CN (CC*NN)
#define GG 8
#define EPSF 1e-8f
#define NT 64

typedef __attribute__((ext_vector_type(8))) short bf16x8;
typedef __attribute__((ext_vector_type(4))) float f32x4;
typedef __attribute__((ext_vector_type(2))) unsigned int uint32x2;

__device__ __forceinline__ unsigned short bfr(float f) {  // f32 -> bf16 RNE
  unsigned int u = __float_as_uint(f);
  return (unsigned short)((u + 0x7FFFu + ((u >> 16) & 1u)) >> 16);
}

// async global->LDS DMA, 16B per lane. LDS dest = base + lane*16 (wave-uniform base).
__device__ __forceinline__ void gload_lds16(const void* g, void* l) {
  __builtin_amdgcn_global_load_lds(
      (__attribute__((address_space(1))) void*)(void*)(size_t)g,
      (__attribute__((address_space(3))) void*)l, 16, 0, 0);
}

// ---------------- prep: x passthrough + xnorm partials + MFMA conv/relu/pool ----------------
// x staged via global_load_lds DMA (no landing VGPRs -> read depth 32KB/block in flight),
// two 32KB halves; LDS readback -> bf16 regions + nontemporal xout + sumsq; conv tail as R18.
// grid: 16 b x 64 n-tiles(64). block 512 = 8 waves. LDS 64.5KB -> 2 blocks/CU.
__global__ __launch_bounds__(512, 4) void k_prep(const float* __restrict__ x,
                                                 const float* __restrict__ conv_w,
                                                 const float* __restrict__ conv_b,
                                                 float* __restrict__ xout,
                                                 float* __restrict__ xnp,
                                                 float* __restrict__ pooledpart,
                                                 unsigned short* __restrict__ xbf_g) {
  const int b = blockIdx.x >> 6;
  const int chunk = blockIdx.x & 63;
  const int t = threadIdx.x;
  const int lane = t & 63, wv = t >> 6;
  __shared__ float xsf[8192];            // 32KB: f32 half-tile, 128 rows x 64 n, linear
  __shared__ unsigned short xbf[16384];  // 32KB: 32 regions [kk][nt], 32x16 each
  __shared__ float pool[8 * 16];

  // A-frags: conv_w (L2-hot) inline-converted
  const int dt = wv >> 1, h2 = wv & 1;
  const int g = lane >> 4, col = lane & 15;
  const int drow = dt * 16 + col;
  union AF { uint4 q; bf16x8 v; unsigned short u[8]; } a[8];
  {
    const float* wrow = conv_w + (size_t)drow * 256;
#pragma unroll
    for (int kk = 0; kk < 8; ++kk) {
      float4 w0 = *(const float4*)(wrow + kk * 32 + g * 8);
      float4 w1 = *(const float4*)(wrow + kk * 32 + g * 8 + 4);
      a[kk].u[0] = bfr(w0.x); a[kk].u[1] = bfr(w0.y);
      a[kk].u[2] = bfr(w0.z); a[kk].u[3] = bfr(w0.w);
      a[kk].u[4] = bfr(w1.x); a[kk].u[5] = bfr(w1.y);
      a[kk].u[6] = bfr(w1.z); a[kk].u[7] = bfr(w1.w);
    }
  }

  const float* xb = x + (size_t)b * CN + chunk * NT;
  float* xo = xout + (size_t)b * CN + chunk * NT;
  const int r0 = t >> 4, j = t & 15;
  float sq[8];

#pragma unroll
  for (int h = 0; h < 2; ++h) {
    // DMA 32KB half: 4 instrs/wave; dest = xsf + blk*256 floats, lane offset 16B
#pragma unroll
    for (int i = 0; i < 4; ++i) {
      const int blk = wv * 4 + i;  // 0..31 -> local rows 4blk..4blk+3
      const float* gp =
          xb + (size_t)(h * 128 + blk * 4 + (lane >> 4)) * NN + (lane & 15) * 4;
      gload_lds16(gp, xsf + blk * 256);
    }
    __syncthreads();  // drains vmcnt -> DMA landed
    // readback: convert + region store + xout + sumsq
#pragma unroll
    for (int k = 0; k < 4; ++k) {
      const int rl = k * 32 + r0;  // local row 0..127
      f32x4 v = *(const f32x4*)&xsf[rl * 64 + j * 4];
      const int kk = h * 4 + k;
      ushort4 hh;
      hh.x = bfr(v.x); hh.y = bfr(v.y); hh.z = bfr(v.z); hh.w = bfr(v.w);
      *(ushort4*)&xbf[(kk * 4 + (j >> 2)) * 512 + r0 * 16 + (j & 3) * 4] = hh;
      __builtin_nontemporal_store(v,
          (f32x4*)(xo + (size_t)(h * 128 + rl) * NN + j * 4));
      sq[kk] = v.x * v.x + v.y * v.y + v.z * v.z + v.w * v.w;
    }
    __syncthreads();  // xsf reads done before next DMA overwrites
  }

#pragma unroll
  for (int k = 0; k < 8; ++k) {
    float s = sq[k];
    s += __shfl_xor(s, 1, 64); s += __shfl_xor(s, 2, 64);
    s += __shfl_xor(s, 4, 64); s += __shfl_xor(s, 8, 64);
    sq[k] = s;
  }
  if ((t & 15) == 0) {
    float* xp = xnp + ((size_t)b * 64 + chunk) * 256 + r0;
#pragma unroll
    for (int k = 0; k < 8; ++k) xp[k * 32] = sq[k];
  }

  // dump bf16 tile to global (region-linear identity copy; overlaps conv below)
  {
    uint4* xgo4 = (uint4*)(xbf_g + (size_t)(b * 64 + chunk) * 16384);
    const uint4* xl4 = (const uint4*)xbf;
#pragma unroll
    for (int k = 0; k < 4; ++k) xgo4[k * 512 + t] = xl4[k * 512 + t];
  }

  // MFMA conv: D[d][n] = sum_c W[d][c] * X[c][n]
  f32x4 acc0 = {0.f, 0.f, 0.f, 0.f}, acc1 = {0.f, 0.f, 0.f, 0.f};
  const unsigned int xbase = (unsigned int)(size_t)&xbf[0];
  const unsigned int lanoff = (unsigned int)(col * 2 + g * 256);
#pragma unroll
  for (int kk = 0; kk < 8; ++kk) {
    const unsigned int ra = xbase + (unsigned int)((kk * 4 + 2 * h2) * 1024) + lanoff;
    const unsigned int rb = ra + 1024;
    union BF { uint32x2 tr[2]; bf16x8 v; } b0, b1;
    asm volatile("ds_read_b64_tr_b16 %0, %1" : "=v"(b0.tr[0]) : "v"(ra));
    asm volatile("ds_read_b64_tr_b16 %0, %1" : "=v"(b0.tr[1]) : "v"(ra + 128));
    asm volatile("ds_read_b64_tr_b16 %0, %1" : "=v"(b1.tr[0]) : "v"(rb));
    asm volatile("ds_read_b64_tr_b16 %0, %1" : "=v"(b1.tr[1]) : "v"(rb + 128));
    asm volatile("s_waitcnt lgkmcnt(0)" ::: "memory");
    __builtin_amdgcn_sched_barrier(0);
    acc0 = __builtin_amdgcn_mfma_f32_16x16x32_bf16(a[kk].v, b0.v, acc0, 0, 0, 0);
    acc1 = __builtin_amdgcn_mfma_f32_16x16x32_bf16(a[kk].v, b1.v, acc1, 0, 0, 0);
  }
  const float4 bias = *(const float4*)(conv_b + dt * 16 + 4 * g);
  const float br[4] = {bias.x, bias.y, bias.z, bias.w};
  float hs[4];
#pragma unroll
  for (int r = 0; r < 4; ++r) {
    float hv = fmaxf(acc0[r] + br[r], 0.f) + fmaxf(acc1[r] + br[r], 0.f);
    hv += __shfl_xor(hv, 1, 64); hv += __shfl_xor(hv, 2, 64);
    hv += __shfl_xor(hv, 4, 64); hv += __shfl_xor(hv, 8, 64);
    hs[r] = hv;
  }
  if (col == 0) {
#pragma unroll
    for (int r = 0; r < 4; ++r) pool[wv * 16 + g * 4 + r] = hs[r];
  }
  __syncthreads();
  if (t < 64) {
    const int dtt = t >> 4, idx = t & 15;
    pooledpart[((size_t)b * 64 + chunk) * 64 + t] =
        pool[(dtt * 2) * 16 + idx] + pool[(dtt * 2 + 1) * 16 + idx];
  }
}

// ---------------- pooled-reduce + logits + softmax -> wgT (bf16 [16][256], rows 8-15 = 0) ---
__global__ __launch_bounds__(256) void k_logits(const float* __restrict__ pooledpart,
                                                const float* __restrict__ lin_w,
                                                const float* __restrict__ lin_b,
                                                const float* __restrict__ ga,
                                                float* __restrict__ logits,
                                                unsigned short* __restrict__ wgT) {
  const int b = blockIdx.x, t = threadIdx.x;
  __shared__ float ps2[4][64];
  __shared__ float ps[64];
  {
    const int d = t & 63, q = t >> 6;
    float s = 0.f;
#pragma unroll
    for (int k = 0; k < 16; ++k)
      s += pooledpart[((size_t)b * 64 + q * 16 + k) * 64 + d];
    ps2[q][d] = s;
  }
  __syncthreads();
  if (t < 64) ps[t] = (ps2[0][t] + ps2[1][t] + ps2[2][t] + ps2[3][t]) * (1.f / 4096.f);
  __syncthreads();
  const int c = t;
  float out[8];
#pragma unroll
  for (int g = 0; g < 8; ++g) {
    const float4* wr = (const float4*)(lin_w + ((size_t)c * 8 + g) * 64);
    float s = 0.f;
#pragma unroll
    for (int k4 = 0; k4 < 16; ++k4) {
      float4 wv = wr[k4];
      s += wv.x * ps[k4 * 4] + wv.y * ps[k4 * 4 + 1] + wv.z * ps[k4 * 4 + 2] +
           wv.w * ps[k4 * 4 + 3];
    }
    out[g] = s + lin_b[c * 8 + g] + logf(ga[((size_t)b * 256 + c) * 8 + g] + EPSF);
  }
  float* lp = logits + ((size_t)b * 256 + c) * 8;
  *(float4*)lp = make_float4(out[0], out[1], out[2], out[3]);
  *(float4*)(lp + 4) = make_float4(out[4], out[5], out[6], out[7]);
  float m = out[0];
#pragma unroll
  for (int g = 1; g < 8; ++g) m = fmaxf(m, out[g]);
  float sum = 0.f;
#pragma unroll
  for (int g = 0; g < 8; ++g) { out[g] = __expf(out[g] - m); sum += out[g]; }
  float r = 1.f / sum;
  unsigned short* wb = wgT + (size_t)b * 4096;
#pragma unroll
  for (int g = 0; g < 8; ++g) wb[g * 256 + c] = bfr(out[g] * r);
#pragma unroll
  for (int g = 8; g < 16; ++g) wb[g * 256 + c] = 0;
}

// ---------------- fused routing iteration, MFMA (DMA-staged bf16 tile) ----------------------
__global__ __launch_bounds__(512) void k_route(const unsigned short* __restrict__ xbf_g,
                                               const unsigned short* __restrict__ wgT,
                                               float* __restrict__ spart2,
                                               float* __restrict__ simpart) {
  const int b = blockIdx.x >> 6;
  const int chunk = blockIdx.x & 63;
  const int t = threadIdx.x;
  const int lane = t & 63, wv = t >> 6;
  const int col = lane & 15, grp = lane >> 4;
  __shared__ unsigned short xbf[16384];
  __shared__ unsigned short stb[1024];
  __shared__ float spool[64];

  // identity stage via DMA: 4 instrs/wave, dest base wave-uniform + lane*16
  {
    const uint4* xg = (const uint4*)xbf_g + (size_t)(b * 64 + chunk) * 2048;
    uint4* xl = (uint4*)xbf;
#pragma unroll
    for (int k = 0; k < 4; ++k) {
      const int base = k * 512 + wv * 64;
      gload_lds16(xg + base + lane, xl + base);
    }
  }
  __syncthreads();

  const unsigned int xbase = (unsigned int)(size_t)&xbf[0];
  const unsigned int sbase = (unsigned int)(size_t)&stb[0];
  const unsigned int lanoff = (unsigned int)(col * 2 + grp * 256);

  // ---- phase 1: waves 0-3, nt = wv ----
  if (wv < 4) {
    const int nt = wv;
    union AF { uint4 q; bf16x8 v; } a[8];
    const uint4* wq = (const uint4*)(wgT + (size_t)b * 4096);
#pragma unroll
    for (int kk = 0; kk < 8; ++kk) a[kk].q = wq[col * 32 + kk * 4 + grp];
    f32x4 acc = {0.f, 0.f, 0.f, 0.f};
#pragma unroll
    for (int kk = 0; kk < 8; ++kk) {
      const unsigned int ra = xbase + (unsigned int)((kk * 4 + nt) * 1024) + lanoff;
      union BF { uint32x2 tr[2]; bf16x8 v; } bf;
      asm volatile("ds_read_b64_tr_b16 %0, %1" : "=v"(bf.tr[0]) : "v"(ra));
      asm volatile("ds_read_b64_tr_b16 %0, %1" : "=v"(bf.tr[1]) : "v"(ra + 128));
      asm volatile("s_waitcnt lgkmcnt(0)" ::: "memory");
      __builtin_amdgcn_sched_barrier(0);
      acc = __builtin_amdgcn_mfma_f32_16x16x32_bf16(a[kk].v, bf.v, acc, 0, 0, 0);
    }
    {
      ushort4 sv4;
      sv4.x = bfr(acc[0]); sv4.y = bfr(acc[1]); sv4.z = bfr(acc[2]); sv4.w = bfr(acc[3]);
      *(ushort4*)&stb[(nt >> 1) * 512 + ((nt & 1) * 16 + col) * 16 + 4 * grp] = sv4;
      float s2[4];
#pragma unroll
      for (int r = 0; r < 4; ++r) {
        float vv = acc[r] * acc[r];
        vv += __shfl_xor(vv, 1, 64); vv += __shfl_xor(vv, 2, 64);
        vv += __shfl_xor(vv, 4, 64); vv += __shfl_xor(vv, 8, 64);
        s2[r] = vv;
      }
      if (col == 0) {
#pragma unroll
        for (int r = 0; r < 4; ++r) spool[nt * 16 + 4 * grp + r] = s2[r];
      }
    }
  }
  __syncthreads();
  if (t < 8)
    spart2[((size_t)b * 64 + chunk) * 8 + t] =
        spool[t] + spool[16 + t] + spool[32 + t] + spool[48 + t];

  // ---- phase 2: all 8 waves, mc = wv*2 + m2 ----
  float* sp = simpart + ((size_t)b * 64 + chunk) * 2048;
#pragma unroll
  for (int m2 = 0; m2 < 2; ++m2) {
    const int mc = wv * 2 + m2;
    const int kkA = mc >> 1;
    const int rowin = (mc & 1) * 16 + col;
    f32x4 acc = {0.f, 0.f, 0.f, 0.f};
#pragma unroll
    for (int kh = 0; kh < 2; ++kh) {
      union AF { uint4 q; bf16x8 v; } aa;
      aa.q = *(const uint4*)&xbf[(kkA * 4 + kh * 2 + (grp >> 1)) * 512 + rowin * 16 +
                                 (grp & 1) * 8];
      const unsigned int rb = sbase + (unsigned int)(kh * 1024) + lanoff;
      union BF { uint32x2 tr[2]; bf16x8 v; } bs;
      asm volatile("ds_read_b64_tr_b16 %0, %1" : "=v"(bs.tr[0]) : "v"(rb));
      asm volatile("ds_read_b64_tr_b16 %0, %1" : "=v"(bs.tr[1]) : "v"(rb + 128));
      asm volatile("s_waitcnt lgkmcnt(0)" ::: "memory");
      __builtin_amdgcn_sched_barrier(0);
      acc = __builtin_amdgcn_mfma_f32_16x16x32_bf16(aa.v, bs.v, acc, 0, 0, 0);
    }
    if (col < 8) {
#pragma unroll
      for (int r = 0; r < 4; ++r)
        sp[(size_t)(mc * 16 + 4 * grp + r) * 8 + col] = acc[r];
    }
  }
}

// ---------------- logits += sim/(xn*sn); !FINAL: softmax->wgT (+xnorm); FINAL: ->d_out ------
template <int FINAL>
__global__ __launch_bounds__(256) void k_upd(const float* __restrict__ simpart,
                                             const float* __restrict__ xnp,
                                             const float* __restrict__ spart2,
                                             float* __restrict__ logits,
                                             float* __restrict__ xnorm,
                                             unsigned short* __restrict__ wgT,
                                             float* __restrict__ outw) {
  const int b = blockIdx.x >> 4;
  const int c0 = (blockIdx.x & 15) * 16;
  const int t = threadIdx.x;
  __shared__ float simld[16][8];
  __shared__ float xnl[16];
  __shared__ float snr8[8];
  {
    const int pair = t >> 1, kh = t & 1;
    const int cl = pair >> 3, g = pair & 7;
    float sm = 0.f;
    const float* sp = simpart + (((size_t)b * 64 + kh * 32) * 256 + c0 + cl) * 8 + g;
#pragma unroll 8
    for (int k = 0; k < 32; ++k) sm += sp[(size_t)k * 2048];
    sm += __shfl_xor(sm, 1, 64);
    if (kh == 0) simld[cl][g] = sm;
  }
  {
    const int cl2 = t >> 4, kq = t & 15;
    if (!FINAL) {
      float p = 0.f;
#pragma unroll
      for (int jj = 0; jj < 4; ++jj)
        p += xnp[((size_t)b * 64 + kq + 16 * jj) * 256 + c0 + cl2];
      p += __shfl_xor(p, 1, 64); p += __shfl_xor(p, 2, 64);
      p += __shfl_xor(p, 4, 64); p += __shfl_xor(p, 8, 64);
      if (kq == 0) {
        float xn = fmaxf(sqrtf(p), EPSF);
        xnl[cl2] = xn;
        xnorm[b * 256 + c0 + cl2] = xn;
      }
    } else {
      if (kq == 0) xnl[cl2] = xnorm[b * 256 + c0 + cl2];
    }
  }
  if (t < 64) {
    const int g2 = t >> 3, kq = t & 7;
    float p = 0.f;
#pragma unroll
    for (int jj = 0; jj < 8; ++jj) p += spart2[((size_t)b * 64 + kq + 8 * jj) * 8 + g2];
    p += __shfl_xor(p, 1, 64); p += __shfl_xor(p, 2, 64); p += __shfl_xor(p, 4, 64);
    if (kq == 0) snr8[g2] = 1.f / fmaxf(sqrtf(p), EPSF);
  }
  __syncthreads();
  if (t < 16) {
    const int c = c0 + t;
    float* lp = logits + ((size_t)b * 256 + c) * 8;
    float4 l0 = *(const float4*)lp, l1 = *(const float4*)(lp + 4);
    float lg[8] = {l0.x, l0.y, l0.z, l0.w, l1.x, l1.y, l1.z, l1.w};
    const float xni = 1.f / xnl[t];
#pragma unroll
    for (int g = 0; g < 8; ++g) lg[g] += simld[t][g] * xni * snr8[g];
    if (!FINAL) {
      *(float4*)lp = make_float4(lg[0], lg[1], lg[2], lg[3]);
      *(float4*)(lp + 4) = make_float4(lg[4], lg[5], lg[6], lg[7]);
    }
    float m = lg[0];
#pragma unroll
    for (int g = 1; g < 8; ++g) m = fmaxf(m, lg[g]);
    float sum = 0.f;
#pragma unroll
    for (int g = 0; g < 8; ++g) { lg[g] = __expf(lg[g] - m); sum += lg[g]; }
    float r = 1.f / sum;
    if (!FINAL) {
      unsigned short* wb = wgT + (size_t)b * 4096;
#pragma unroll
      for (int g = 0; g < 8; ++g) wb[g * 256 + c] = bfr(lg[g] * r);
#pragma unroll
      for (int g = 8; g < 16; ++g) wb[g * 256 + c] = 0;
    } else {
      float4* op = (float4*)(outw + ((size_t)b * 256 + c) * 8);
      op[0] = make_float4(lg[0] * r, lg[1] * r, lg[2] * r, lg[3] * r);
      op[1] = make_float4(lg[4] * r, lg[5] * r, lg[6] * r, lg[7] * r);
    }
  }
}

extern "C" void kernel_launch(void* const* d_in, const int* in_sizes, int n_in,
                              void* d_out, int out_size, void* d_ws, size_t ws_size,
                              hipStream_t stream) {
  const float* x = (const float*)d_in[0];
  const float* ga = (const float*)d_in[1];
  const float* conv_w = (const float*)d_in[2];
  const float* conv_b = (const float*)d_in[3];
  const float* lin_w = (const float*)d_in[4];
  const float* lin_b = (const float*)d_in[5];
  float* out = (float*)d_out;
  float* outx = out + 32768;  // x passthrough region

  float* ws = (float*)d_ws;
  float* pooledpart = ws;                               // 65536
  float* logits = ws + 81920;                           // 32768
  unsigned short* wgT = (unsigned short*)(ws + 114688); // 65536 ushort
  float* xnorm = ws + 147456;                           // 4096
  float* xnp = ws + 151552;                             // 262144
  float* spart2 = ws + 413696;                          // 8192
  float* simpart = ws + 421888;                         // 2097152
  unsigned short* xbf_g = (unsigned short*)(ws + 2519040);  // 16.8M ushort (33.5MB)

  k_prep<<<1024, 512, 0, stream>>>(x, conv_w, conv_b, outx, xnp, pooledpart, xbf_g);
  k_logits<<<16, 256, 0, stream>>>(pooledpart, lin_w, lin_b, ga, logits, wgT);

  // iteration 1
  k_route<<<1024, 512, 0, stream>>>(xbf_g, wgT, spart2, simpart);
  k_upd<0><<<256, 256, 0, stream>>>(simpart, xnp, spart2, logits, xnorm, wgT, out);

  // iteration 2 (+ final softmax into d_out)
  k_route<<<1024, 512, 0, stream>>>(xbf_g, wgT, spart2, simpart);
  k_upd<1><<<256, 256, 0, stream>>>(simpart, xnp, spart2, logits, xnorm, wgT, out);
}

// Round 22
// 87.666 us; speedup vs baseline: 1.0328x; 1.0328x over previous
//
#include <hip/hip_runtime.h>

#define BB 16
#define CC 256
#define NN 4096
#define CN (CC*NN)
#define GG 8
#define EPSF 1e-8f
#define NT 64

typedef __attribute__((ext_vector_type(8))) short bf16x8;
typedef __attribute__((ext_vector_type(4))) float f32x4;
typedef __attribute__((ext_vector_type(2))) unsigned int uint32x2;

__device__ __forceinline__ unsigned short bfr(float f) {  // f32 -> bf16 RNE
  unsigned int u = __float_as_uint(f);
  return (unsigned short)((u + 0x7FFFu + ((u >> 16) & 1u)) >> 16);
}

// ---------------- prep: x passthrough + xnorm partials + MFMA conv/relu/pool ----------------
// + dumps the bf16 region-layout x tile to xbf_g (consumed by both k_route calls).
// grid: 16 b x 64 n-tiles(64). block 512 = 8 waves. (R18 champion configuration.)
__global__ __launch_bounds__(512, 2) void k_prep(const float* __restrict__ x,
                                                 const float* __restrict__ conv_w,
                                                 const float* __restrict__ conv_b,
                                                 float* __restrict__ xout,
                                                 float* __restrict__ xnp,
                                                 float* __restrict__ pooledpart,
                                                 unsigned short* __restrict__ xbf_g) {
  const int b = blockIdx.x >> 6;
  const int chunk = blockIdx.x & 63;
  const int t = threadIdx.x;
  const int lane = t & 63, wv = t >> 6;
  __shared__ unsigned short xbf[16384];  // 32 KB: 32 regions [kk=c/32][nt=n/16], 32x16 each
  __shared__ float pool[8 * 16];

  // A-frags first: independent global loads (L2-hot), converted inline.
  const int dt = wv >> 1, h2 = wv & 1;
  const int g = lane >> 4, col = lane & 15;
  const int drow = dt * 16 + col;
  union AF { uint4 q; bf16x8 v; unsigned short u[8]; } a[8];
  {
    const float* wrow = conv_w + (size_t)drow * 256;
#pragma unroll
    for (int kk = 0; kk < 8; ++kk) {
      float4 w0 = *(const float4*)(wrow + kk * 32 + g * 8);
      float4 w1 = *(const float4*)(wrow + kk * 32 + g * 8 + 4);
      a[kk].u[0] = bfr(w0.x); a[kk].u[1] = bfr(w0.y);
      a[kk].u[2] = bfr(w0.z); a[kk].u[3] = bfr(w0.w);
      a[kk].u[4] = bfr(w1.x); a[kk].u[5] = bfr(w1.y);
      a[kk].u[6] = bfr(w1.z); a[kk].u[7] = bfr(w1.w);
    }
  }

  // stage x tile: rows c = k*32 + r0 (r0 = t>>4), float4-col j = t&15
  const float* xb = x + (size_t)b * CN + chunk * NT;
  const int r0 = t >> 4, j = t & 15;
  f32x4 v[8];
  float sq[8];
#pragma unroll
  for (int k = 0; k < 8; ++k)
    v[k] = *(const f32x4*)(xb + (size_t)(k * 32 + r0) * NN + j * 4);
#pragma unroll
  for (int k = 0; k < 8; ++k) {
    ushort4 hh;
    hh.x = bfr(v[k].x); hh.y = bfr(v[k].y); hh.z = bfr(v[k].z); hh.w = bfr(v[k].w);
    *(ushort4*)&xbf[(k * 4 + (j >> 2)) * 512 + r0 * 16 + (j & 3) * 4] = hh;
    sq[k] = v[k].x * v[k].x + v[k].y * v[k].y + v[k].z * v[k].z + v[k].w * v[k].w;
  }
  float* xo = xout + (size_t)b * CN + chunk * NT;
#pragma unroll
  for (int k = 0; k < 8; ++k)
    __builtin_nontemporal_store(v[k],
        (f32x4*)(xo + (size_t)(k * 32 + r0) * NN + j * 4));
#pragma unroll
  for (int k = 0; k < 8; ++k) {
    float s = sq[k];
    s += __shfl_xor(s, 1, 64); s += __shfl_xor(s, 2, 64);
    s += __shfl_xor(s, 4, 64); s += __shfl_xor(s, 8, 64);
    sq[k] = s;
  }
  if ((t & 15) == 0) {
    float* xp = xnp + ((size_t)b * 64 + chunk) * 256 + r0;
#pragma unroll
    for (int k = 0; k < 8; ++k) xp[k * 32] = sq[k];
  }
  __syncthreads();

  // dump bf16 tile to global (region-linear identity copy; overlaps conv below)
  {
    uint4* xgo4 = (uint4*)(xbf_g + (size_t)(b * 64 + chunk) * 16384);
    const uint4* xl4 = (const uint4*)xbf;
#pragma unroll
    for (int k = 0; k < 4; ++k) xgo4[k * 512 + t] = xl4[k * 512 + t];
  }

  // MFMA conv: D[d][n] = sum_c W[d][c] * X[c][n]
  f32x4 acc0 = {0.f, 0.f, 0.f, 0.f}, acc1 = {0.f, 0.f, 0.f, 0.f};
  const unsigned int xbase = (unsigned int)(size_t)&xbf[0];
  const unsigned int lanoff = (unsigned int)(col * 2 + g * 256);
#pragma unroll
  for (int kk = 0; kk < 8; ++kk) {
    const unsigned int ra = xbase + (unsigned int)((kk * 4 + 2 * h2) * 1024) + lanoff;
    const unsigned int rb = ra + 1024;
    union BF { uint32x2 tr[2]; bf16x8 v; } b0, b1;
    asm volatile("ds_read_b64_tr_b16 %0, %1" : "=v"(b0.tr[0]) : "v"(ra));
    asm volatile("ds_read_b64_tr_b16 %0, %1" : "=v"(b0.tr[1]) : "v"(ra + 128));
    asm volatile("ds_read_b64_tr_b16 %0, %1" : "=v"(b1.tr[0]) : "v"(rb));
    asm volatile("ds_read_b64_tr_b16 %0, %1" : "=v"(b1.tr[1]) : "v"(rb + 128));
    asm volatile("s_waitcnt lgkmcnt(0)" ::: "memory");
    __builtin_amdgcn_sched_barrier(0);
    acc0 = __builtin_amdgcn_mfma_f32_16x16x32_bf16(a[kk].v, b0.v, acc0, 0, 0, 0);
    acc1 = __builtin_amdgcn_mfma_f32_16x16x32_bf16(a[kk].v, b1.v, acc1, 0, 0, 0);
  }
  const float4 bias = *(const float4*)(conv_b + dt * 16 + 4 * g);
  const float br[4] = {bias.x, bias.y, bias.z, bias.w};
  float hs[4];
#pragma unroll
  for (int r = 0; r < 4; ++r) {
    float hv = fmaxf(acc0[r] + br[r], 0.f) + fmaxf(acc1[r] + br[r], 0.f);
    hv += __shfl_xor(hv, 1, 64); hv += __shfl_xor(hv, 2, 64);
    hv += __shfl_xor(hv, 4, 64); hv += __shfl_xor(hv, 8, 64);
    hs[r] = hv;
  }
  if (col == 0) {
#pragma unroll
    for (int r = 0; r < 4; ++r) pool[wv * 16 + g * 4 + r] = hs[r];
  }
  __syncthreads();
  if (t < 64) {
    const int dtt = t >> 4, idx = t & 15;
    pooledpart[((size_t)b * 64 + chunk) * 64 + t] =
        pool[(dtt * 2) * 16 + idx] + pool[(dtt * 2 + 1) * 16 + idx];
  }
}

// ---------------- pooled-reduce + logits + softmax -> wgT (bf16 [16][256], rows 8-15 = 0) ---
__global__ __launch_bounds__(256) void k_logits(const float* __restrict__ pooledpart,
                                                const float* __restrict__ lin_w,
                                                const float* __restrict__ lin_b,
                                                const float* __restrict__ ga,
                                                float* __restrict__ logits,
                                                unsigned short* __restrict__ wgT) {
  const int b = blockIdx.x, t = threadIdx.x;
  __shared__ float ps2[4][64];
  __shared__ float ps[64];
  {
    const int d = t & 63, q = t >> 6;
    float s = 0.f;
#pragma unroll
    for (int k = 0; k < 16; ++k)
      s += pooledpart[((size_t)b * 64 + q * 16 + k) * 64 + d];
    ps2[q][d] = s;
  }
  __syncthreads();
  if (t < 64) ps[t] = (ps2[0][t] + ps2[1][t] + ps2[2][t] + ps2[3][t]) * (1.f / 4096.f);
  __syncthreads();
  const int c = t;
  float out[8];
#pragma unroll
  for (int g = 0; g < 8; ++g) {
    const float4* wr = (const float4*)(lin_w + ((size_t)c * 8 + g) * 64);
    float s = 0.f;
#pragma unroll
    for (int k4 = 0; k4 < 16; ++k4) {
      float4 wv = wr[k4];
      s += wv.x * ps[k4 * 4] + wv.y * ps[k4 * 4 + 1] + wv.z * ps[k4 * 4 + 2] +
           wv.w * ps[k4 * 4 + 3];
    }
    out[g] = s + lin_b[c * 8 + g] + logf(ga[((size_t)b * 256 + c) * 8 + g] + EPSF);
  }
  float* lp = logits + ((size_t)b * 256 + c) * 8;
  *(float4*)lp = make_float4(out[0], out[1], out[2], out[3]);
  *(float4*)(lp + 4) = make_float4(out[4], out[5], out[6], out[7]);
  float m = out[0];
#pragma unroll
  for (int g = 1; g < 8; ++g) m = fmaxf(m, out[g]);
  float sum = 0.f;
#pragma unroll
  for (int g = 0; g < 8; ++g) { out[g] = __expf(out[g] - m); sum += out[g]; }
  float r = 1.f / sum;
  unsigned short* wb = wgT + (size_t)b * 4096;
#pragma unroll
  for (int g = 0; g < 8; ++g) wb[g * 256 + c] = bfr(out[g] * r);
#pragma unroll
  for (int g = 8; g < 16; ++g) wb[g * 256 + c] = 0;
}

// ---------------- fused routing iteration, MFMA (stages pre-converted bf16 tile) ------------
__global__ __launch_bounds__(512) void k_route(const unsigned short* __restrict__ xbf_g,
                                               const unsigned short* __restrict__ wgT,
                                               float* __restrict__ spart2,
                                               float* __restrict__ simpart) {
  const int b = blockIdx.x >> 6;
  const int chunk = blockIdx.x & 63;
  const int t = threadIdx.x;
  const int lane = t & 63, wv = t >> 6;
  const int col = lane & 15, grp = lane >> 4;
  __shared__ unsigned short xbf[16384];
  __shared__ unsigned short stb[1024];
  __shared__ float spool[64];

  {
    const uint4* xg = (const uint4*)xbf_g + (size_t)(b * 64 + chunk) * 2048;
    uint4* xl = (uint4*)xbf;
#pragma unroll
    for (int k = 0; k < 4; ++k) xl[k * 512 + t] = xg[k * 512 + t];
  }
  __syncthreads();

  const unsigned int xbase = (unsigned int)(size_t)&xbf[0];
  const unsigned int sbase = (unsigned int)(size_t)&stb[0];
  const unsigned int lanoff = (unsigned int)(col * 2 + grp * 256);

  // ---- phase 1: waves 0-3, nt = wv ----
  if (wv < 4) {
    const int nt = wv;
    union AF { uint4 q; bf16x8 v; } a[8];
    const uint4* wq = (const uint4*)(wgT + (size_t)b * 4096);
#pragma unroll
    for (int kk = 0; kk < 8; ++kk) a[kk].q = wq[col * 32 + kk * 4 + grp];
    f32x4 acc = {0.f, 0.f, 0.f, 0.f};
#pragma unroll
    for (int kk = 0; kk < 8; ++kk) {
      const unsigned int ra = xbase + (unsigned int)((kk * 4 + nt) * 1024) + lanoff;
      union BF { uint32x2 tr[2]; bf16x8 v; } bf;
      asm volatile("ds_read_b64_tr_b16 %0, %1" : "=v"(bf.tr[0]) : "v"(ra));
      asm volatile("ds_read_b64_tr_b16 %0, %1" : "=v"(bf.tr[1]) : "v"(ra + 128));
      asm volatile("s_waitcnt lgkmcnt(0)" ::: "memory");
      __builtin_amdgcn_sched_barrier(0);
      acc = __builtin_amdgcn_mfma_f32_16x16x32_bf16(a[kk].v, bf.v, acc, 0, 0, 0);
    }
    {
      ushort4 sv4;
      sv4.x = bfr(acc[0]); sv4.y = bfr(acc[1]); sv4.z = bfr(acc[2]); sv4.w = bfr(acc[3]);
      *(ushort4*)&stb[(nt >> 1) * 512 + ((nt & 1) * 16 + col) * 16 + 4 * grp] = sv4;
      float s2[4];
#pragma unroll
      for (int r = 0; r < 4; ++r) {
        float vv = acc[r] * acc[r];
        vv += __shfl_xor(vv, 1, 64); vv += __shfl_xor(vv, 2, 64);
        vv += __shfl_xor(vv, 4, 64); vv += __shfl_xor(vv, 8, 64);
        s2[r] = vv;
      }
      if (col == 0) {
#pragma unroll
        for (int r = 0; r < 4; ++r) spool[nt * 16 + 4 * grp + r] = s2[r];
      }
    }
  }
  __syncthreads();
  if (t < 8)
    spart2[((size_t)b * 64 + chunk) * 8 + t] =
        spool[t] + spool[16 + t] + spool[32 + t] + spool[48 + t];

  // ---- phase 2: all 8 waves, mc = wv*2 + m2 ----
  float* sp = simpart + ((size_t)b * 64 + chunk) * 2048;
#pragma unroll
  for (int m2 = 0; m2 < 2; ++m2) {
    const int mc = wv * 2 + m2;
    const int kkA = mc >> 1;
    const int rowin = (mc & 1) * 16 + col;
    f32x4 acc = {0.f, 0.f, 0.f, 0.f};
#pragma unroll
    for (int kh = 0; kh < 2; ++kh) {
      union AF { uint4 q; bf16x8 v; } aa;
      aa.q = *(const uint4*)&xbf[(kkA * 4 + kh * 2 + (grp >> 1)) * 512 + rowin * 16 +
                                 (grp & 1) * 8];
      const unsigned int rb = sbase + (unsigned int)(kh * 1024) + lanoff;
      union BF { uint32x2 tr[2]; bf16x8 v; } bs;
      asm volatile("ds_read_b64_tr_b16 %0, %1" : "=v"(bs.tr[0]) : "v"(rb));
      asm volatile("ds_read_b64_tr_b16 %0, %1" : "=v"(bs.tr[1]) : "v"(rb + 128));
      asm volatile("s_waitcnt lgkmcnt(0)" ::: "memory");
      __builtin_amdgcn_sched_barrier(0);
      acc = __builtin_amdgcn_mfma_f32_16x16x32_bf16(aa.v, bs.v, acc, 0, 0, 0);
    }
    if (col < 8) {
#pragma unroll
      for (int r = 0; r < 4; ++r)
        sp[(size_t)(mc * 16 + 4 * grp + r) * 8 + col] = acc[r];
    }
  }
}

// ---------------- logits += sim/(xn*sn); !FINAL: softmax->wgT (+xnorm); FINAL: ->d_out ------
template <int FINAL>
__global__ __launch_bounds__(256) void k_upd(const float* __restrict__ simpart,
                                             const float* __restrict__ xnp,
                                             const float* __restrict__ spart2,
                                             float* __restrict__ logits,
                                             float* __restrict__ xnorm,
                                             unsigned short* __restrict__ wgT,
                                             float* __restrict__ outw) {
  const int b = blockIdx.x >> 4;
  const int c0 = (blockIdx.x & 15) * 16;
  const int t = threadIdx.x;
  __shared__ float simld[16][8];
  __shared__ float xnl[16];
  __shared__ float snr8[8];
  {
    const int pair = t >> 1, kh = t & 1;
    const int cl = pair >> 3, g = pair & 7;
    float sm = 0.f;
    const float* sp = simpart + (((size_t)b * 64 + kh * 32) * 256 + c0 + cl) * 8 + g;
#pragma unroll 8
    for (int k = 0; k < 32; ++k) sm += sp[(size_t)k * 2048];
    sm += __shfl_xor(sm, 1, 64);
    if (kh == 0) simld[cl][g] = sm;
  }
  {
    const int cl2 = t >> 4, kq = t & 15;
    if (!FINAL) {
      float p = 0.f;
#pragma unroll
      for (int jj = 0; jj < 4; ++jj)
        p += xnp[((size_t)b * 64 + kq + 16 * jj) * 256 + c0 + cl2];
      p += __shfl_xor(p, 1, 64); p += __shfl_xor(p, 2, 64);
      p += __shfl_xor(p, 4, 64); p += __shfl_xor(p, 8, 64);
      if (kq == 0) {
        float xn = fmaxf(sqrtf(p), EPSF);
        xnl[cl2] = xn;
        xnorm[b * 256 + c0 + cl2] = xn;
      }
    } else {
      if (kq == 0) xnl[cl2] = xnorm[b * 256 + c0 + cl2];
    }
  }
  if (t < 64) {
    const int g2 = t >> 3, kq = t & 7;
    float p = 0.f;
#pragma unroll
    for (int jj = 0; jj < 8; ++jj) p += spart2[((size_t)b * 64 + kq + 8 * jj) * 8 + g2];
    p += __shfl_xor(p, 1, 64); p += __shfl_xor(p, 2, 64); p += __shfl_xor(p, 4, 64);
    if (kq == 0) snr8[g2] = 1.f / fmaxf(sqrtf(p), EPSF);
  }
  __syncthreads();
  if (t < 16) {
    const int c = c0 + t;
    float* lp = logits + ((size_t)b * 256 + c) * 8;
    float4 l0 = *(const float4*)lp, l1 = *(const float4*)(lp + 4);
    float lg[8] = {l0.x, l0.y, l0.z, l0.w, l1.x, l1.y, l1.z, l1.w};
    const float xni = 1.f / xnl[t];
#pragma unroll
    for (int g = 0; g < 8; ++g) lg[g] += simld[t][g] * xni * snr8[g];
    if (!FINAL) {
      *(float4*)lp = make_float4(lg[0], lg[1], lg[2], lg[3]);
      *(float4*)(lp + 4) = make_float4(lg[4], lg[5], lg[6], lg[7]);
    }
    float m = lg[0];
#pragma unroll
    for (int g = 1; g < 8; ++g) m = fmaxf(m, lg[g]);
    float sum = 0.f;
#pragma unroll
    for (int g = 0; g < 8; ++g) { lg[g] = __expf(lg[g] - m); sum += lg[g]; }
    float r = 1.f / sum;
    if (!FINAL) {
      unsigned short* wb = wgT + (size_t)b * 4096;
#pragma unroll
      for (int g = 0; g < 8; ++g) wb[g * 256 + c] = bfr(lg[g] * r);
#pragma unroll
      for (int g = 8; g < 16; ++g) wb[g * 256 + c] = 0;
    } else {
      float4* op = (float4*)(outw + ((size_t)b * 256 + c) * 8);
      op[0] = make_float4(lg[0] * r, lg[1] * r, lg[2] * r, lg[3] * r);
      op[1] = make_float4(lg[4] * r, lg[5] * r, lg[6] * r, lg[7] * r);
    }
  }
}

extern "C" void kernel_launch(void* const* d_in, const int* in_sizes, int n_in,
                              void* d_out, int out_size, void* d_ws, size_t ws_size,
                              hipStream_t stream) {
  const float* x = (const float*)d_in[0];
  const float* ga = (const float*)d_in[1];
  const float* conv_w = (const float*)d_in[2];
  const float* conv_b = (const float*)d_in[3];
  const float* lin_w = (const float*)d_in[4];
  const float* lin_b = (const float*)d_in[5];
  float* out = (float*)d_out;
  float* outx = out + 32768;  // x passthrough region

  float* ws = (float*)d_ws;
  float* pooledpart = ws;                               // 65536
  float* logits = ws + 81920;                           // 32768
  unsigned short* wgT = (unsigned short*)(ws + 114688); // 65536 ushort
  float* xnorm = ws + 147456;                           // 4096
  float* xnp = ws + 151552;                             // 262144
  float* spart2 = ws + 413696;                          // 8192
  float* simpart = ws + 421888;                         // 2097152
  unsigned short* xbf_g = (unsigned short*)(ws + 2519040);  // 16.8M ushort (33.5MB)

  k_prep<<<1024, 512, 0, stream>>>(x, conv_w, conv_b, outx, xnp, pooledpart, xbf_g);
  k_logits<<<16, 256, 0, stream>>>(pooledpart, lin_w, lin_b, ga, logits, wgT);

  // iteration 1
  k_route<<<1024, 512, 0, stream>>>(xbf_g, wgT, spart2, simpart);
  k_upd<0><<<256, 256, 0, stream>>>(simpart, xnp, spart2, logits, xnorm, wgT, out);

  // iteration 2 (+ final softmax into d_out)
  k_route<<<1024, 512, 0, stream>>>(xbf_g, wgT, spart2, simpart);
  k_upd<1><<<256, 256, 0, stream>>>(simpart, xnp, spart2, logits, xnorm, wgT, out);
}